// Round 5
// baseline (6515.189 us; speedup 1.0000x reference)
//
#include <hip/hip_runtime.h>
#include <hip/hip_bf16.h>
#include <math.h>

// Problem constants (fixed by the reference)
#define NB   8
#define SL   2048
#define DM   512
#define DI   1024
#define NDS  64
#define DTR  32
#define NROWS (NB*SL)   // 16384

#define TCH 8    // scan time-chunk (register-resident, double-buffered)
#define NC  16   // parallel-scan chunks over L
#define LC  (SL/NC)  // 128 steps per chunk

typedef __attribute__((ext_vector_type(8))) short short8;
typedef __attribute__((ext_vector_type(4))) float f32x4;

__device__ __forceinline__ float sigmoidf_(float x){ return 1.0f/(1.0f + __expf(-x)); }

// ---------------- fallback: zero the output (ws too small diagnostic) -------
__global__ void __launch_bounds__(256) zero_kernel(float* __restrict__ p, int n)
{
  const int i = blockIdx.x*256 + threadIdx.x;
  if (i < n) p[i] = 0.0f;
}

// ---------------- f32 -> bf16 elementwise convert ----------------
__global__ void __launch_bounds__(256) cvt_bf16_kernel(const float* __restrict__ s,
    __hip_bfloat16* __restrict__ d, int n)
{
  const int i = blockIdx.x*256 + threadIdx.x;
  if (i < n) d[i] = __float2bfloat16(s[i]);
}

// ---------------- LayerNorm: one wave per row, bf16 output ----------------
__global__ void __launch_bounds__(256) ln_kernel(const float* __restrict__ x,
    const float* __restrict__ w, const float* __restrict__ b,
    __hip_bfloat16* __restrict__ out)
{
  const int wave = threadIdx.x >> 6;
  const int lane = threadIdx.x & 63;
  const int row  = (blockIdx.x << 2) + wave;
  const float* xr = x + (size_t)row * DM;
  float4 v0 = *(const float4*)(xr + lane*4);
  float4 v1 = *(const float4*)(xr + 256 + lane*4);
  float s = v0.x+v0.y+v0.z+v0.w + v1.x+v1.y+v1.z+v1.w;
  float q = v0.x*v0.x+v0.y*v0.y+v0.z*v0.z+v0.w*v0.w
          + v1.x*v1.x+v1.y*v1.y+v1.z*v1.z+v1.w*v1.w;
  #pragma unroll
  for (int off=1; off<64; off<<=1){ s += __shfl_xor(s, off); q += __shfl_xor(q, off); }
  const float mean = s * (1.0f/DM);
  const float var  = q * (1.0f/DM) - mean*mean;
  const float rstd = rsqrtf(var + 1e-5f);
  float4 w0 = *(const float4*)(w + lane*4);
  float4 w1 = *(const float4*)(w + 256 + lane*4);
  float4 b0 = *(const float4*)(b + lane*4);
  float4 b1 = *(const float4*)(b + 256 + lane*4);
  __hip_bfloat16* orow = out + (size_t)row * DM;
  orow[lane*4+0] = __float2bfloat16((v0.x-mean)*rstd*w0.x + b0.x);
  orow[lane*4+1] = __float2bfloat16((v0.y-mean)*rstd*w0.y + b0.y);
  orow[lane*4+2] = __float2bfloat16((v0.z-mean)*rstd*w0.z + b0.z);
  orow[lane*4+3] = __float2bfloat16((v0.w-mean)*rstd*w0.w + b0.w);
  orow[256+lane*4+0] = __float2bfloat16((v1.x-mean)*rstd*w1.x + b1.x);
  orow[256+lane*4+1] = __float2bfloat16((v1.y-mean)*rstd*w1.y + b1.y);
  orow[256+lane*4+2] = __float2bfloat16((v1.z-mean)*rstd*w1.z + b1.z);
  orow[256+lane*4+3] = __float2bfloat16((v1.w-mean)*rstd*w1.w + b1.w);
}

// ---------------- bf16 MFMA GEMM: C[M,N] = A[M,K] * W[N,K]^T (+res) --------
// 128x128 tile, BK=32, 4 waves, each wave 64x64 via 4x4 of 16x16x32 MFMA.
// LDS rows padded to 40 ushorts (80 B): 2-way bank aliasing only (free, m136).
template<typename OutT, bool HasRes>
__global__ void __launch_bounds__(256) gemm_mfma(
    const ushort* __restrict__ A, const ushort* __restrict__ W,
    OutT* __restrict__ C, const float* __restrict__ res,
    int M, int N, int K)
{
  __shared__ __align__(16) ushort As[128*40];
  __shared__ __align__(16) ushort Ws[128*40];
  const int t    = threadIdx.x;
  const int m0   = blockIdx.y * 128;
  const int n0   = blockIdx.x * 128;
  const int lane = t & 63;
  const int wv   = t >> 6;
  const int wm   = wv >> 1, wn = wv & 1;
  const int fr   = lane & 15, fq = lane >> 4;

  const int ar0 = t >> 2,        as0 = (t & 3) << 3;
  const int ar1 = (t+256) >> 2,  as1 = as0;
  const int wr0 = min(n0 + ar0, N-1);
  const int wr1 = min(n0 + ar1, N-1);

  f32x4 acc[4][4];
  #pragma unroll
  for (int i=0;i<4;i++)
    #pragma unroll
    for (int j=0;j<4;j++) acc[i][j] = (f32x4){0.f,0.f,0.f,0.f};

  const ushort* Ab = A + (size_t)m0 * K;

  for (int k0 = 0; k0 < K; k0 += 32) {
    const int4 av0 = *(const int4*)(Ab + (size_t)ar0*K + k0 + as0);
    const int4 av1 = *(const int4*)(Ab + (size_t)ar1*K + k0 + as1);
    const int4 wv0 = *(const int4*)(W  + (size_t)wr0*K + k0 + as0);
    const int4 wv1 = *(const int4*)(W  + (size_t)wr1*K + k0 + as1);
    *(int4*)&As[ar0*40 + as0] = av0;
    *(int4*)&As[ar1*40 + as1] = av1;
    *(int4*)&Ws[ar0*40 + as0] = wv0;
    *(int4*)&Ws[ar1*40 + as1] = wv1;
    __syncthreads();
    short8 af[4], wf[4];
    #pragma unroll
    for (int i=0;i<4;i++)
      af[i] = *(const short8*)&As[(wm*64 + i*16 + fr)*40 + fq*8];
    #pragma unroll
    for (int j=0;j<4;j++)
      wf[j] = *(const short8*)&Ws[(wn*64 + j*16 + fr)*40 + fq*8];
    #pragma unroll
    for (int i=0;i<4;i++)
      #pragma unroll
      for (int j=0;j<4;j++)
        acc[i][j] = __builtin_amdgcn_mfma_f32_16x16x32_bf16(af[i], wf[j], acc[i][j], 0, 0, 0);
    __syncthreads();
  }

  #pragma unroll
  for (int j=0;j<4;j++){
    const int n = n0 + wn*64 + j*16 + fr;
    if (n >= N) continue;
    #pragma unroll
    for (int i=0;i<4;i++){
      #pragma unroll
      for (int r=0;r<4;r++){
        const int m = m0 + wm*64 + i*16 + fq*4 + r;
        float v = acc[i][j][r];
        if (HasRes) v += res[(size_t)m*N + n];
        if (sizeof(OutT) == 2)
          ((__hip_bfloat16*)C)[(size_t)m*N + n] = __float2bfloat16(v);
        else
          ((float*)C)[(size_t)m*N + n] = v;
      }
    }
  }
}

// ---------------- Causal depthwise conv (width 4) + SiLU, bf16 in/out -------
__global__ void __launch_bounds__(256) conv_silu_kernel(
    const __hip_bfloat16* __restrict__ u_raw,
    const float* __restrict__ cw, const float* __restrict__ cb,
    __hip_bfloat16* __restrict__ uc)
{
  const int gid = blockIdx.x*256 + threadIdx.x;     // 0 .. NROWS*DI-1
  const int d   = gid & (DI-1);
  const int row = gid >> 10;
  const int l   = row & (SL-1);
  float acc = cb[d];
  const float* w = cw + d*4;
  #pragma unroll
  for (int k=0;k<4;k++){
    const int ll = l-3+k;
    if (ll >= 0) acc += __bfloat162float(u_raw[(size_t)(row-3+k)*DI + d]) * w[k];
  }
  const float s = acc * sigmoidf_(acc);
  uc[gid] = __float2bfloat16(s);
}

// ---------------- dt = softplus(dt_part @ dtp_w^T + b) ----------------
__global__ void __launch_bounds__(256) dt_kernel(const float* __restrict__ xdbl,
    const float* __restrict__ w, const float* __restrict__ bias, float* __restrict__ dt_out)
{
  const int d     = blockIdx.y*256 + threadIdx.x;
  const int rbase = blockIdx.x*64;
  float wr[32];
  #pragma unroll
  for (int i=0;i<8;i++){
    const float4 v = *(const float4*)(w + (size_t)d*DTR + i*4);
    wr[i*4+0]=v.x; wr[i*4+1]=v.y; wr[i*4+2]=v.z; wr[i*4+3]=v.w;
  }
  const float bb = bias[d];
  __shared__ __align__(16) float xd[64][32];
  #pragma unroll
  for (int ii=0; ii<2; ii++){
    const int i  = threadIdx.x + ii*256;
    const int rl = i >> 3, qo = (i & 7) << 2;
    const float4 v = *(const float4*)(xdbl + (size_t)(rbase+rl)*160 + qo);
    *(float4*)&xd[rl][qo] = v;
  }
  __syncthreads();
  for (int rl=0; rl<64; rl++){
    float acc = bb;
    #pragma unroll
    for (int r=0;r<DTR;r++) acc += xd[rl][r]*wr[r];
    const float sp = (acc > 20.0f) ? acc : logf(1.0f + __expf(acc));
    dt_out[(size_t)(rbase+rl)*DI + d] = sp;
  }
}

// ================= Chunked parallel selective scan =================
// Recurrence h[t] = dA[t] h[t-1] + dB[t]u[t] is linear: split L into NC
// chunks of LC. pass1 runs the h-recurrence per chunk from h=0 (no y),
// storing h_end and sum(dt); pass2 propagates chunk-boundary states
// (exp(a*sum_dt) == prod(dA) up to rounding); pass3 re-runs the full
// per-step recurrence from the true h_start, producing y.
// Wave mapping (all passes): 4 d-channels/wave, lane = (dl=lane>>4, sg=lane&15),
// 4 states/lane; p-reduction over sg via 4 shfl_xor.

struct P1Step { float dt, u; float4 B; };

__device__ __forceinline__ void p1_load_chunk(P1Step s[TCH],
    const float* __restrict__ dtp, const __hip_bfloat16* __restrict__ up,
    const float* __restrict__ bp, int base)
{
  #pragma unroll
  for (int t=0; t<TCH; t++){
    const size_t o  = (size_t)(base+t)*DI;
    const size_t o2 = (size_t)(base+t)*160;
    s[t].dt = dtp[o];
    s[t].u  = __bfloat162float(up[o]);
    s[t].B  = *(const float4*)(bp + o2);
  }
}

// grid: (64 d-blocks, NC chunks, NB batches), block 256 = 4 waves x 4 d
__global__ void __launch_bounds__(256, 4) scan_pass1(
    const float* __restrict__ dt_s, const __hip_bfloat16* __restrict__ uc,
    const float* __restrict__ xdbl, const float* __restrict__ A_log,
    float* __restrict__ hbuf, float* __restrict__ dtsum)
{
  const int wave  = threadIdx.x >> 6;
  const int lane  = threadIdx.x & 63;
  const int c     = blockIdx.y;
  const int batch = blockIdx.z;
  const int dl = lane >> 4, sg = lane & 15;
  const int d  = blockIdx.x*16 + wave*4 + dl;

  const float a0 = -__expf(A_log[(size_t)d*NDS + sg*4 + 0]);
  const float a1 = -__expf(A_log[(size_t)d*NDS + sg*4 + 1]);
  const float a2 = -__expf(A_log[(size_t)d*NDS + sg*4 + 2]);
  const float a3 = -__expf(A_log[(size_t)d*NDS + sg*4 + 3]);
  float h0=0.f,h1=0.f,h2=0.f,h3=0.f, sdt=0.f;

  const size_t r0 = (size_t)batch * SL + (size_t)c * LC;
  const float*          dtp = dt_s + r0*DI + d;
  const __hip_bfloat16* up  = uc   + r0*DI + d;
  const float*          bp  = xdbl + r0*160 + 32 + (sg<<2);

  P1Step buf0[TCH], buf1[TCH];
  p1_load_chunk(buf0, dtp, up, bp, 0);
  for (int base = 0; base < LC; base += 2*TCH) {
    p1_load_chunk(buf1, dtp, up, bp, base + TCH);
    #pragma unroll
    for (int t=0; t<TCH; t++){
      const P1Step& s = buf0[t];
      const float dtu = s.dt * s.u;
      sdt += s.dt;
      h0 = __expf(s.dt*a0)*h0 + dtu*s.B.x;
      h1 = __expf(s.dt*a1)*h1 + dtu*s.B.y;
      h2 = __expf(s.dt*a2)*h2 + dtu*s.B.z;
      h3 = __expf(s.dt*a3)*h3 + dtu*s.B.w;
    }
    if (base + 2*TCH < LC)
      p1_load_chunk(buf0, dtp, up, bp, base + 2*TCH);
    #pragma unroll
    for (int t=0; t<TCH; t++){
      const P1Step& s = buf1[t];
      const float dtu = s.dt * s.u;
      sdt += s.dt;
      h0 = __expf(s.dt*a0)*h0 + dtu*s.B.x;
      h1 = __expf(s.dt*a1)*h1 + dtu*s.B.y;
      h2 = __expf(s.dt*a2)*h2 + dtu*s.B.z;
      h3 = __expf(s.dt*a3)*h3 + dtu*s.B.w;
    }
  }
  const size_t hidx = ((((size_t)c*NB + batch)*DI + d)*NDS) + (sg<<2);
  *(float4*)&hbuf[hidx] = make_float4(h0,h1,h2,h3);
  if (sg == 0) dtsum[((size_t)c*NB + batch)*DI + d] = sdt;
}

// chunk-state propagation, in-place: hbuf[c] := h_start[c]
// tid -> (b = tid>>16, d = (tid>>6)&1023, s = tid&63)
__global__ void __launch_bounds__(256) scan_pass2(
    const float* __restrict__ A_log, const float* __restrict__ dtsum,
    float* __restrict__ hbuf)
{
  const int tid = blockIdx.x*256 + threadIdx.x;
  const int s = tid & 63, d = (tid >> 6) & (DI-1), b = tid >> 16;
  const float a = -__expf(A_log[(size_t)d*NDS + s]);
  float h = 0.f;
  for (int c = 0; c < NC; c++){
    const size_t idx = (((size_t)c*NB + b)*DI + d)*NDS + s;
    const float he = hbuf[idx];
    hbuf[idx] = h;                                   // h_start for chunk c
    h = __expf(a * dtsum[((size_t)c*NB + b)*DI + d]) * h + he;
  }
}

struct ScanStep { float dt, u, z; float4 B, C; };

__device__ __forceinline__ void scan_load_chunk(ScanStep s[TCH],
    const float* __restrict__ dtp, const __hip_bfloat16* __restrict__ up,
    const __hip_bfloat16* __restrict__ zp,
    const float* __restrict__ bp, const float* __restrict__ cp, int base)
{
  #pragma unroll
  for (int t=0; t<TCH; t++){
    const size_t o  = (size_t)(base+t)*DI;
    const size_t o2 = (size_t)(base+t)*160;
    s[t].dt = dtp[o];
    s[t].u  = __bfloat162float(up[o]);
    s[t].z  = __bfloat162float(zp[o]);
    s[t].B  = *(const float4*)(bp + o2);
    s[t].C  = *(const float4*)(cp + o2);
  }
}

// grid: (64 d-blocks, NC chunks, NB batches)
__global__ void __launch_bounds__(256, 3) scan_pass3(
    const float* __restrict__ dt_s, const __hip_bfloat16* __restrict__ uc,
    const __hip_bfloat16* __restrict__ zb, const float* __restrict__ xdbl,
    const float* __restrict__ A_log, const float* __restrict__ Dv,
    const float* __restrict__ hbuf, __hip_bfloat16* __restrict__ yg)
{
  const int wave  = threadIdx.x >> 6;
  const int lane  = threadIdx.x & 63;
  const int c     = blockIdx.y;
  const int batch = blockIdx.z;
  const int dl = lane >> 4, sg = lane & 15;
  const int d  = blockIdx.x*16 + wave*4 + dl;

  const float a0 = -__expf(A_log[(size_t)d*NDS + sg*4 + 0]);
  const float a1 = -__expf(A_log[(size_t)d*NDS + sg*4 + 1]);
  const float a2 = -__expf(A_log[(size_t)d*NDS + sg*4 + 2]);
  const float a3 = -__expf(A_log[(size_t)d*NDS + sg*4 + 3]);
  const float Dval = Dv[d];

  const size_t hidx = ((((size_t)c*NB + batch)*DI + d)*NDS) + (sg<<2);
  const float4 hs = *(const float4*)&hbuf[hidx];
  float h0=hs.x, h1=hs.y, h2=hs.z, h3=hs.w;

  const size_t r0 = (size_t)batch * SL + (size_t)c * LC;
  const float*          dtp = dt_s + r0*DI + d;
  const __hip_bfloat16* up  = uc   + r0*DI + d;
  const __hip_bfloat16* zp  = zb   + r0*DI + d;
  const float*          bp  = xdbl + r0*160 + 32 + (sg<<2);
  const float*          cp  = xdbl + r0*160 + 96 + (sg<<2);
  __hip_bfloat16*       yp  = yg   + r0*DI + d;

  ScanStep buf0[TCH], buf1[TCH];
  scan_load_chunk(buf0, dtp, up, zp, bp, cp, 0);

  for (int base = 0; base < LC; base += 2*TCH) {
    scan_load_chunk(buf1, dtp, up, zp, bp, cp, base + TCH);
    #pragma unroll
    for (int t=0; t<TCH; t++){
      const ScanStep& s = buf0[t];
      const float dtu = s.dt * s.u;
      h0 = __expf(s.dt*a0)*h0 + dtu*s.B.x;
      h1 = __expf(s.dt*a1)*h1 + dtu*s.B.y;
      h2 = __expf(s.dt*a2)*h2 + dtu*s.B.z;
      h3 = __expf(s.dt*a3)*h3 + dtu*s.B.w;
      float p = h0*s.C.x + h1*s.C.y + h2*s.C.z + h3*s.C.w;
      p += __shfl_xor(p,1); p += __shfl_xor(p,2);
      p += __shfl_xor(p,4); p += __shfl_xor(p,8);
      if (sg == 0) {
        const float y = p + s.u*Dval;
        yp[(size_t)(base+t)*DI] = __float2bfloat16(y * s.z * sigmoidf_(s.z));
      }
    }
    if (base + 2*TCH < LC)
      scan_load_chunk(buf0, dtp, up, zp, bp, cp, base + 2*TCH);
    #pragma unroll
    for (int t=0; t<TCH; t++){
      const ScanStep& s = buf1[t];
      const float dtu = s.dt * s.u;
      h0 = __expf(s.dt*a0)*h0 + dtu*s.B.x;
      h1 = __expf(s.dt*a1)*h1 + dtu*s.B.y;
      h2 = __expf(s.dt*a2)*h2 + dtu*s.B.z;
      h3 = __expf(s.dt*a3)*h3 + dtu*s.B.w;
      float p = h0*s.C.x + h1*s.C.y + h2*s.C.z + h3*s.C.w;
      p += __shfl_xor(p,1); p += __shfl_xor(p,2);
      p += __shfl_xor(p,4); p += __shfl_xor(p,8);
      if (sg == 0) {
        const float y = p + s.u*Dval;
        yp[(size_t)(base+TCH+t)*DI] = __float2bfloat16(y * s.z * sigmoidf_(s.z));
      }
    }
  }
}

extern "C" void kernel_launch(void* const* d_in, const int* in_sizes, int n_in,
                              void* d_out, int out_size, void* d_ws, size_t ws_size,
                              hipStream_t stream)
{
  const float* x      = (const float*)d_in[0];
  const float* ln_w   = (const float*)d_in[1];
  const float* ln_b   = (const float*)d_in[2];
  const float* inpw   = (const float*)d_in[3];
  const float* convw  = (const float*)d_in[4];
  const float* convb  = (const float*)d_in[5];
  const float* xpw    = (const float*)d_in[6];
  const float* dtpw   = (const float*)d_in[7];
  const float* dtpb   = (const float*)d_in[8];
  const float* A_log  = (const float*)d_in[9];
  const float* Dmat   = (const float*)d_in[10];
  const float* outw   = (const float*)d_in[11];
  float* out = (float*)d_out;

  // Workspace (~233 MB, under the round-2-proven 235 MB):
  const size_t nIn   = (size_t)2*DI*DM;
  const size_t nXp   = (size_t)160*DI;
  const size_t nOutW = (size_t)DM*DI;
  size_t off = 0;
  char* base = (char*)d_ws;
  auto alloc = [&](size_t bytes)->char*{ char* p = base + off; off += (bytes + 255) & ~(size_t)255; return p; };
  __hip_bfloat16* hln   = (__hip_bfloat16*)alloc((size_t)NROWS*DM*2);
  __hip_bfloat16* ubf   = (__hip_bfloat16*)alloc((size_t)NROWS*DI*2);  // u_raw, then y
  __hip_bfloat16* zbf   = (__hip_bfloat16*)alloc((size_t)NROWS*DI*2);
  __hip_bfloat16* ucb   = (__hip_bfloat16*)alloc((size_t)NROWS*DI*2);
  float*          xdb   = (float*)alloc((size_t)NROWS*160*4);
  float*          dtb   = (float*)alloc((size_t)NROWS*DI*4);
  __hip_bfloat16* wIn   = (__hip_bfloat16*)alloc(nIn*2);
  __hip_bfloat16* wXp   = (__hip_bfloat16*)alloc(nXp*2);
  __hip_bfloat16* wOut  = (__hip_bfloat16*)alloc(nOutW*2);
  float*          hbuf  = (float*)alloc((size_t)NC*NB*DI*NDS*4);   // 33.6 MB
  float*          dts   = (float*)alloc((size_t)NC*NB*DI*4);       // 0.5 MB
  if (ws_size < off) {
    zero_kernel<<<(out_size+255)/256, 256, 0, stream>>>(out, out_size);
    return;
  }

  for (int l = 0; l < 2; ++l) {
    const float* xin = (l == 0) ? x : out;
    cvt_bf16_kernel<<<(int)((nIn  +255)/256), 256, 0, stream>>>(inpw + (size_t)l*nIn,  wIn,  (int)nIn);
    cvt_bf16_kernel<<<(int)((nXp  +255)/256), 256, 0, stream>>>(xpw  + (size_t)l*nXp,  wXp,  (int)nXp);
    cvt_bf16_kernel<<<(int)((nOutW+255)/256), 256, 0, stream>>>(outw + (size_t)l*nOutW, wOut, (int)nOutW);

    ln_kernel<<<NROWS/4, 256, 0, stream>>>(xin, ln_w + l*DM, ln_b + l*DM, hln);

    gemm_mfma<__hip_bfloat16,false><<<dim3(DI/128, NROWS/128), 256, 0, stream>>>(
        (const ushort*)hln, (const ushort*)wIn, ubf, nullptr, NROWS, DI, DM);
    gemm_mfma<__hip_bfloat16,false><<<dim3(DI/128, NROWS/128), 256, 0, stream>>>(
        (const ushort*)hln, (const ushort*)(wIn + (size_t)DI*DM), zbf, nullptr, NROWS, DI, DM);

    conv_silu_kernel<<<(NROWS*DI)/256, 256, 0, stream>>>(
        ubf, convw + l*DI*4, convb + l*DI, ucb);

    gemm_mfma<float,false><<<dim3(2, NROWS/128), 256, 0, stream>>>(
        (const ushort*)ucb, (const ushort*)wXp, xdb, nullptr, NROWS, 160, DI);

    dt_kernel<<<dim3(NROWS/64, DI/256), 256, 0, stream>>>(
        xdb, dtpw + (size_t)l*DI*DTR, dtpb + l*DI, dtb);

    const float* Al = A_log + (size_t)l*DI*NDS;
    scan_pass1<<<dim3(64, NC, NB), 256, 0, stream>>>(dtb, ucb, xdb, Al, hbuf, dts);
    scan_pass2<<<(NB*DI*NDS)/256, 256, 0, stream>>>(Al, dts, hbuf);
    scan_pass3<<<dim3(64, NC, NB), 256, 0, stream>>>(
        dtb, ucb, zbf, xdb, Al, Dmat + l*DI, hbuf, ubf);

    gemm_mfma<float,true><<<dim3(DM/128, NROWS/128), 256, 0, stream>>>(
        (const ushort*)ubf, (const ushort*)wOut, out, xin, NROWS, DM, DI);
  }
}

// Round 6
// 3742.018 us; speedup vs baseline: 1.7411x; 1.7411x over previous
//
#include <hip/hip_runtime.h>
#include <hip/hip_bf16.h>
#include <math.h>

// Problem constants (fixed by the reference)
#define NB   8
#define SL   2048
#define DM   512
#define DI   1024
#define NDS  64
#define DTR  32
#define NROWS (NB*SL)   // 16384

#define NC  8          // parallel-scan chunks over L
#define LC  (SL/NC)    // 256 steps per chunk
#define TCH 4          // register-resident time-chunk (double-buffered)

typedef __attribute__((ext_vector_type(8))) short short8;
typedef __attribute__((ext_vector_type(4))) float f32x4;

__device__ __forceinline__ float sigmoidf_(float x){ return 1.0f/(1.0f + __expf(-x)); }
__device__ __forceinline__ float bfbits_(unsigned int hi){ return __uint_as_float(hi); }

// ---------------- fallback: zero the output (ws too small diagnostic) -------
__global__ void __launch_bounds__(256) zero_kernel(float* __restrict__ p, int n)
{
  const int i = blockIdx.x*256 + threadIdx.x;
  if (i < n) p[i] = 0.0f;
}

// ---------------- f32 -> bf16 elementwise convert ----------------
__global__ void __launch_bounds__(256) cvt_bf16_kernel(const float* __restrict__ s,
    __hip_bfloat16* __restrict__ d, int n)
{
  const int i = blockIdx.x*256 + threadIdx.x;
  if (i < n) d[i] = __float2bfloat16(s[i]);
}

// ---------------- LayerNorm: one wave per row, bf16 output ----------------
__global__ void __launch_bounds__(256) ln_kernel(const float* __restrict__ x,
    const float* __restrict__ w, const float* __restrict__ b,
    __hip_bfloat16* __restrict__ out)
{
  const int wave = threadIdx.x >> 6;
  const int lane = threadIdx.x & 63;
  const int row  = (blockIdx.x << 2) + wave;
  const float* xr = x + (size_t)row * DM;
  float4 v0 = *(const float4*)(xr + lane*4);
  float4 v1 = *(const float4*)(xr + 256 + lane*4);
  float s = v0.x+v0.y+v0.z+v0.w + v1.x+v1.y+v1.z+v1.w;
  float q = v0.x*v0.x+v0.y*v0.y+v0.z*v0.z+v0.w*v0.w
          + v1.x*v1.x+v1.y*v1.y+v1.z*v1.z+v1.w*v1.w;
  #pragma unroll
  for (int off=1; off<64; off<<=1){ s += __shfl_xor(s, off); q += __shfl_xor(q, off); }
  const float mean = s * (1.0f/DM);
  const float var  = q * (1.0f/DM) - mean*mean;
  const float rstd = rsqrtf(var + 1e-5f);
  float4 w0 = *(const float4*)(w + lane*4);
  float4 w1 = *(const float4*)(w + 256 + lane*4);
  float4 b0 = *(const float4*)(b + lane*4);
  float4 b1 = *(const float4*)(b + 256 + lane*4);
  __hip_bfloat16* orow = out + (size_t)row * DM;
  orow[lane*4+0] = __float2bfloat16((v0.x-mean)*rstd*w0.x + b0.x);
  orow[lane*4+1] = __float2bfloat16((v0.y-mean)*rstd*w0.y + b0.y);
  orow[lane*4+2] = __float2bfloat16((v0.z-mean)*rstd*w0.z + b0.z);
  orow[lane*4+3] = __float2bfloat16((v0.w-mean)*rstd*w0.w + b0.w);
  orow[256+lane*4+0] = __float2bfloat16((v1.x-mean)*rstd*w1.x + b1.x);
  orow[256+lane*4+1] = __float2bfloat16((v1.y-mean)*rstd*w1.y + b1.y);
  orow[256+lane*4+2] = __float2bfloat16((v1.z-mean)*rstd*w1.z + b1.z);
  orow[256+lane*4+3] = __float2bfloat16((v1.w-mean)*rstd*w1.w + b1.w);
}

// ---------------- bf16 MFMA GEMM: C[M,N] = A[M,K] * W[N,K]^T ----------------
// 128x128 tile, BK=32, 4 waves x (4x4 of 16x16x32 MFMA). LDS rows padded to
// 40 ushorts (2-way bank aliasing only = free). Verified round 4.
// MODE: 0 = f32 out, 1 = f32 out + residual, 2 = bf16 row-major out,
//       3 = bf16 TIME-MAJOR out: out[((b*DI+n)*SL)+l], b=m>>11, l=m&2047
template<int MODE>
__global__ void __launch_bounds__(256) gemm_mfma(
    const ushort* __restrict__ A, const ushort* __restrict__ W,
    void* __restrict__ Cout, const float* __restrict__ res,
    int M, int N, int K)
{
  __shared__ __align__(16) ushort As[128*40];
  __shared__ __align__(16) ushort Ws[128*40];
  const int t    = threadIdx.x;
  const int m0   = blockIdx.y * 128;
  const int n0   = blockIdx.x * 128;
  const int lane = t & 63;
  const int wv   = t >> 6;
  const int wm   = wv >> 1, wn = wv & 1;
  const int fr   = lane & 15, fq = lane >> 4;

  const int ar0 = t >> 2,        as0 = (t & 3) << 3;
  const int ar1 = (t+256) >> 2,  as1 = as0;
  const int wr0 = min(n0 + ar0, N-1);
  const int wr1 = min(n0 + ar1, N-1);

  f32x4 acc[4][4];
  #pragma unroll
  for (int i=0;i<4;i++)
    #pragma unroll
    for (int j=0;j<4;j++) acc[i][j] = (f32x4){0.f,0.f,0.f,0.f};

  const ushort* Ab = A + (size_t)m0 * K;

  for (int k0 = 0; k0 < K; k0 += 32) {
    const int4 av0 = *(const int4*)(Ab + (size_t)ar0*K + k0 + as0);
    const int4 av1 = *(const int4*)(Ab + (size_t)ar1*K + k0 + as1);
    const int4 wv0 = *(const int4*)(W  + (size_t)wr0*K + k0 + as0);
    const int4 wv1 = *(const int4*)(W  + (size_t)wr1*K + k0 + as1);
    *(int4*)&As[ar0*40 + as0] = av0;
    *(int4*)&As[ar1*40 + as1] = av1;
    *(int4*)&Ws[ar0*40 + as0] = wv0;
    *(int4*)&Ws[ar1*40 + as1] = wv1;
    __syncthreads();
    short8 af[4], wf[4];
    #pragma unroll
    for (int i=0;i<4;i++)
      af[i] = *(const short8*)&As[(wm*64 + i*16 + fr)*40 + fq*8];
    #pragma unroll
    for (int j=0;j<4;j++)
      wf[j] = *(const short8*)&Ws[(wn*64 + j*16 + fr)*40 + fq*8];
    #pragma unroll
    for (int i=0;i<4;i++)
      #pragma unroll
      for (int j=0;j<4;j++)
        acc[i][j] = __builtin_amdgcn_mfma_f32_16x16x32_bf16(af[i], wf[j], acc[i][j], 0, 0, 0);
    __syncthreads();
  }

  #pragma unroll
  for (int j=0;j<4;j++){
    const int n = n0 + wn*64 + j*16 + fr;
    if (n >= N) continue;
    #pragma unroll
    for (int i=0;i<4;i++){
      const int mb = m0 + wm*64 + i*16 + fq*4;
      if (MODE == 3) {
        const int b = mb >> 11, l = mb & 2047;     // SL = 2048
        ushort4 pk;
        pk.x = __bfloat16_as_ushort(__float2bfloat16(acc[i][j][0]));
        pk.y = __bfloat16_as_ushort(__float2bfloat16(acc[i][j][1]));
        pk.z = __bfloat16_as_ushort(__float2bfloat16(acc[i][j][2]));
        pk.w = __bfloat16_as_ushort(__float2bfloat16(acc[i][j][3]));
        *(ushort4*)((ushort*)Cout + ((size_t)b*DI + n)*SL + l) = pk;
      } else {
        #pragma unroll
        for (int r=0;r<4;r++){
          const int m = mb + r;
          float v = acc[i][j][r];
          if (MODE == 1) v += res[(size_t)m*N + n];
          if (MODE == 2)
            ((__hip_bfloat16*)Cout)[(size_t)m*N + n] = __float2bfloat16(v);
          else
            ((float*)Cout)[(size_t)m*N + n] = v;
        }
      }
    }
  }
}

// ---------------- Causal depthwise conv (width 4) + SiLU, bf16 in/out -------
__global__ void __launch_bounds__(256) conv_silu_kernel(
    const __hip_bfloat16* __restrict__ u_raw,
    const float* __restrict__ cw, const float* __restrict__ cb,
    __hip_bfloat16* __restrict__ uc)
{
  const int gid = blockIdx.x*256 + threadIdx.x;     // 0 .. NROWS*DI-1
  const int d   = gid & (DI-1);
  const int row = gid >> 10;
  const int l   = row & (SL-1);
  float acc = cb[d];
  const float* w = cw + d*4;
  #pragma unroll
  for (int k=0;k<4;k++){
    const int ll = l-3+k;
    if (ll >= 0) acc += __bfloat162float(u_raw[(size_t)(row-3+k)*DI + d]) * w[k];
  }
  const float s = acc * sigmoidf_(acc);
  uc[gid] = __float2bfloat16(s);
}

// ---------------- dt_pack: dt = softplus(xdb[:, :32] @ dtp_w^T + b), --------
// written TIME-MAJOR f32, and uc copied to time-major bf16.
// grid (SL/64, DI/64, NB), block 256. Wave w handles l-quad w, lanes = 64 d.
__global__ void __launch_bounds__(256) dt_pack_kernel(
    const float* __restrict__ xdb, const float* __restrict__ dtpw,
    const float* __restrict__ dtpb, const ushort* __restrict__ ucrow,
    float* __restrict__ dtT, ushort* __restrict__ uT)
{
  __shared__ float xd[64][33];
  const int t = threadIdx.x;
  const int row0 = blockIdx.z*SL + blockIdx.x*64;
  const int d0   = blockIdx.y*64;
  {
    const int r = t >> 2, q = (t & 3) * 8;
    const float4 v0 = *(const float4*)(xdb + (size_t)(row0+r)*160 + q);
    const float4 v1 = *(const float4*)(xdb + (size_t)(row0+r)*160 + q + 4);
    *(float4*)&xd[r][q]   = v0;   // stride 33: not 16B aligned for odd r,
    *(float4*)&xd[r][q+4] = v1;   // compiler lowers to b32/b64 stores - fine
  }
  __syncthreads();
  const int d  = d0 + (t & 63);
  const int lq = t >> 6;                     // 0..3 (== wave)
  float w[32];
  #pragma unroll
  for (int i=0;i<8;i++){
    const float4 v = *(const float4*)(dtpw + (size_t)d*DTR + i*4);
    w[i*4]=v.x; w[i*4+1]=v.y; w[i*4+2]=v.z; w[i*4+3]=v.w;
  }
  const float bb = dtpb[d];
  float dtv[16]; ushort uv[16];
  #pragma unroll
  for (int i=0;i<16;i++){
    const int l = lq*16 + i;
    float acc = bb;
    #pragma unroll
    for (int k=0;k<DTR;k++) acc += xd[l][k]*w[k];
    dtv[i] = (acc > 20.0f) ? acc : logf(1.0f + __expf(acc));
    uv[i]  = ucrow[(size_t)(row0+l)*DI + d];
  }
  float* dp  = dtT + ((size_t)(blockIdx.z*DI + d))*SL + blockIdx.x*64 + lq*16;
  ushort* up = uT  + ((size_t)(blockIdx.z*DI + d))*SL + blockIdx.x*64 + lq*16;
  #pragma unroll
  for (int i=0;i<4;i++) *(float4*)(dp + i*4) = *(float4*)&dtv[i*4];
  #pragma unroll
  for (int i=0;i<2;i++) *(uint4*)(up + i*8) = *(uint4*)&uv[i*8];
}

// ---------------- bc_pack: B,C cols of xdb -> [b][sg][l] {B4,C4} f32 --------
// grid (SL/64, NB), block 256.
__global__ void __launch_bounds__(256) bc_pack_kernel(
    const float* __restrict__ xdb, float* __restrict__ bc)
{
  __shared__ float sb[64][132];   // cols 0..63 = B states, 64..127 = C states
  const int t = threadIdx.x;
  const int row0 = blockIdx.y*SL + blockIdx.x*64;
  {
    const int r = t >> 2, g = t & 3;
    #pragma unroll
    for (int ii=0; ii<8; ii++){
      const int idx = g*8 + ii;           // 0..31 float4 slots (128 floats)
      const float4 v = *(const float4*)(xdb + (size_t)(row0+r)*160 + 32 + idx*4);
      *(float4*)&sb[r][idx*4] = v;        // stride 132: 16B-aligned (132%4==0,
    }                                     // (r*132+idx*4)*4 % 16 == 0)
  }
  __syncthreads();
  const int sg = t & 15, lg = t >> 4;     // lg 0..15, 4 l each
  float* dst = bc + (((size_t)(blockIdx.y*16 + sg))*SL + blockIdx.x*64 + lg*4)*8;
  #pragma unroll
  for (int i=0;i<4;i++){
    const int l = lg*4 + i;
    float4 B, C;
    B.x = sb[l][4*sg+0]; B.y = sb[l][4*sg+1]; B.z = sb[l][4*sg+2]; B.w = sb[l][4*sg+3];
    C.x = sb[l][64+4*sg+0]; C.y = sb[l][64+4*sg+1]; C.z = sb[l][64+4*sg+2]; C.w = sb[l][64+4*sg+3];
    *(float4*)(dst + i*8)     = B;
    *(float4*)(dst + i*8 + 4) = C;
  }
}

// ================= Chunked parallel selective scan =================
// Streams are TIME-MAJOR: per (b,d) contiguous in l -> chunk loads are a few
// dwordx4 with immediate offsets (round-4 profile: strided scalar loads +
// 64-bit addr math were ~half the 254 issue-cyc/step).
// Wave: 4 d-channels, lane=(dl=lane>>4, sg=lane&15), 4 states/lane.

struct C1 { float4 dt; uint2 u; float4 B[TCH]; };
__device__ __forceinline__ void ld1(C1& s, const float* dp, const ushort* up,
                                    const float* bp, int base)
{
  s.dt = *(const float4*)(dp + base);
  s.u  = *(const uint2*)(up + base);
  #pragma unroll
  for (int t=0;t<TCH;t++) s.B[t] = *(const float4*)(bp + (size_t)(base+t)*8);
}

// grid (DI/16, NC, NB), block 256 = 4 waves x 4 d. No min-waves bound (spill!)
__global__ void __launch_bounds__(256) scan_pass1(
    const float* __restrict__ dtT, const ushort* __restrict__ uT,
    const float* __restrict__ bc, const float* __restrict__ A_log,
    float* __restrict__ hbuf, float* __restrict__ dtsum)
{
  const int wave = threadIdx.x >> 6;
  const int lane = threadIdx.x & 63;
  const int c = blockIdx.y, b = blockIdx.z;
  const int dl = lane >> 4, sg = lane & 15;
  const int d  = blockIdx.x*16 + wave*4 + dl;

  const float a0 = -__expf(A_log[(size_t)d*NDS + sg*4 + 0]);
  const float a1 = -__expf(A_log[(size_t)d*NDS + sg*4 + 1]);
  const float a2 = -__expf(A_log[(size_t)d*NDS + sg*4 + 2]);
  const float a3 = -__expf(A_log[(size_t)d*NDS + sg*4 + 3]);
  float h0=0.f,h1=0.f,h2=0.f,h3=0.f, sdt=0.f;

  const float*  dp = dtT + ((size_t)(b*DI + d))*SL + c*LC;
  const ushort* up = uT  + ((size_t)(b*DI + d))*SL + c*LC;
  const float*  bp = bc  + (((size_t)(b*16 + sg))*SL + c*LC)*8;

  C1 A, B;
  ld1(A, dp, up, bp, 0);
  for (int base = 0; base < LC; base += 2*TCH) {
    ld1(B, dp, up, bp, base + TCH);
    #pragma unroll
    for (int t=0;t<TCH;t++){
      const float dtv = ((const float*)&A.dt)[t];
      const unsigned int uw = ((const unsigned int*)&A.u)[t>>1];
      const float uu = bfbits_((t&1) ? (uw & 0xffff0000u) : (uw << 16));
      const float dtu = dtv*uu;  sdt += dtv;
      h0 = __expf(dtv*a0)*h0 + dtu*A.B[t].x;
      h1 = __expf(dtv*a1)*h1 + dtu*A.B[t].y;
      h2 = __expf(dtv*a2)*h2 + dtu*A.B[t].z;
      h3 = __expf(dtv*a3)*h3 + dtu*A.B[t].w;
    }
    if (base + 2*TCH < LC) ld1(A, dp, up, bp, base + 2*TCH);
    #pragma unroll
    for (int t=0;t<TCH;t++){
      const float dtv = ((const float*)&B.dt)[t];
      const unsigned int uw = ((const unsigned int*)&B.u)[t>>1];
      const float uu = bfbits_((t&1) ? (uw & 0xffff0000u) : (uw << 16));
      const float dtu = dtv*uu;  sdt += dtv;
      h0 = __expf(dtv*a0)*h0 + dtu*B.B[t].x;
      h1 = __expf(dtv*a1)*h1 + dtu*B.B[t].y;
      h2 = __expf(dtv*a2)*h2 + dtu*B.B[t].z;
      h3 = __expf(dtv*a3)*h3 + dtu*B.B[t].w;
    }
  }
  const size_t hidx = (((size_t)c*NB + b)*DI + d)*NDS + (sg<<2);
  *(float4*)&hbuf[hidx] = make_float4(h0,h1,h2,h3);
  if (sg == 0) dtsum[((size_t)c*NB + b)*DI + d] = sdt;
}

// chunk-state propagation, in-place: hbuf[c] := h_start[c]
__global__ void __launch_bounds__(256) scan_pass2(
    const float* __restrict__ A_log, const float* __restrict__ dtsum,
    float* __restrict__ hbuf)
{
  const int tid = blockIdx.x*256 + threadIdx.x;
  const int s = tid & 63, d = (tid >> 6) & (DI-1), b = tid >> 16;
  const float a = -__expf(A_log[(size_t)d*NDS + s]);
  float h = 0.f;
  #pragma unroll
  for (int c = 0; c < NC; c++){
    const size_t idx = (((size_t)c*NB + b)*DI + d)*NDS + s;
    const float he = hbuf[idx];
    hbuf[idx] = h;
    h = __expf(a * dtsum[((size_t)c*NB + b)*DI + d]) * h + he;
  }
}

struct C3 { float4 dt; uint2 u, z; float4 B[TCH], C[TCH]; };
__device__ __forceinline__ void ld3(C3& s, const float* dp, const ushort* up,
                                    const ushort* zp, const float* bp, int base)
{
  s.dt = *(const float4*)(dp + base);
  s.u  = *(const uint2*)(up + base);
  s.z  = *(const uint2*)(zp + base);
  #pragma unroll
  for (int t=0;t<TCH;t++){
    s.B[t] = *(const float4*)(bp + (size_t)(base+t)*8);
    s.C[t] = *(const float4*)(bp + (size_t)(base+t)*8 + 4);
  }
}

// grid (DI/16, NC, NB)
__global__ void __launch_bounds__(256) scan_pass3(
    const float* __restrict__ dtT, const ushort* __restrict__ uT,
    const ushort* __restrict__ zT, const float* __restrict__ bc,
    const float* __restrict__ A_log, const float* __restrict__ Dv,
    const float* __restrict__ hbuf, __hip_bfloat16* __restrict__ yg)
{
  const int wave = threadIdx.x >> 6;
  const int lane = threadIdx.x & 63;
  const int c = blockIdx.y, b = blockIdx.z;
  const int dl = lane >> 4, sg = lane & 15;
  const int d  = blockIdx.x*16 + wave*4 + dl;

  const float a0 = -__expf(A_log[(size_t)d*NDS + sg*4 + 0]);
  const float a1 = -__expf(A_log[(size_t)d*NDS + sg*4 + 1]);
  const float a2 = -__expf(A_log[(size_t)d*NDS + sg*4 + 2]);
  const float a3 = -__expf(A_log[(size_t)d*NDS + sg*4 + 3]);
  const float Dval = Dv[d];

  const size_t hidx = (((size_t)c*NB + b)*DI + d)*NDS + (sg<<2);
  const float4 hs = *(const float4*)&hbuf[hidx];
  float h0=hs.x, h1=hs.y, h2=hs.z, h3=hs.w;

  const float*  dp = dtT + ((size_t)(b*DI + d))*SL + c*LC;
  const ushort* up = uT  + ((size_t)(b*DI + d))*SL + c*LC;
  const ushort* zp = zT  + ((size_t)(b*DI + d))*SL + c*LC;
  const float*  bp = bc  + (((size_t)(b*16 + sg))*SL + c*LC)*8;
  __hip_bfloat16* yp = yg + ((size_t)(b*SL + c*LC))*DI + d;

  C3 A, B;
  ld3(A, dp, up, zp, bp, 0);
  for (int base = 0; base < LC; base += 2*TCH) {
    ld3(B, dp, up, zp, bp, base + TCH);
    #pragma unroll
    for (int t=0;t<TCH;t++){
      const float dtv = ((const float*)&A.dt)[t];
      const unsigned int uw = ((const unsigned int*)&A.u)[t>>1];
      const unsigned int zw = ((const unsigned int*)&A.z)[t>>1];
      const float uu = bfbits_((t&1) ? (uw & 0xffff0000u) : (uw << 16));
      const float zz = bfbits_((t&1) ? (zw & 0xffff0000u) : (zw << 16));
      const float dtu = dtv*uu;
      h0 = __expf(dtv*a0)*h0 + dtu*A.B[t].x;
      h1 = __expf(dtv*a1)*h1 + dtu*A.B[t].y;
      h2 = __expf(dtv*a2)*h2 + dtu*A.B[t].z;
      h3 = __expf(dtv*a3)*h3 + dtu*A.B[t].w;
      float p = h0*A.C[t].x + h1*A.C[t].y + h2*A.C[t].z + h3*A.C[t].w;
      p += __shfl_xor(p,1); p += __shfl_xor(p,2);
      p += __shfl_xor(p,4); p += __shfl_xor(p,8);
      if (sg == 0) {
        const float y = p + uu*Dval;
        yp[(size_t)(base+t)*DI] = __float2bfloat16(y * zz * sigmoidf_(zz));
      }
    }
    if (base + 2*TCH < LC) ld3(A, dp, up, zp, bp, base + 2*TCH);
    #pragma unroll
    for (int t=0;t<TCH;t++){
      const float dtv = ((const float*)&B.dt)[t];
      const unsigned int uw = ((const unsigned int*)&B.u)[t>>1];
      const unsigned int zw = ((const unsigned int*)&B.z)[t>>1];
      const float uu = bfbits_((t&1) ? (uw & 0xffff0000u) : (uw << 16));
      const float zz = bfbits_((t&1) ? (zw & 0xffff0000u) : (zw << 16));
      const float dtu = dtv*uu;
      h0 = __expf(dtv*a0)*h0 + dtu*B.B[t].x;
      h1 = __expf(dtv*a1)*h1 + dtu*B.B[t].y;
      h2 = __expf(dtv*a2)*h2 + dtu*B.B[t].z;
      h3 = __expf(dtv*a3)*h3 + dtu*B.B[t].w;
      float p = h0*B.C[t].x + h1*B.C[t].y + h2*B.C[t].z + h3*B.C[t].w;
      p += __shfl_xor(p,1); p += __shfl_xor(p,2);
      p += __shfl_xor(p,4); p += __shfl_xor(p,8);
      if (sg == 0) {
        const float y = p + uu*Dval;
        yp[(size_t)(base+TCH+t)*DI] = __float2bfloat16(y * zz * sigmoidf_(zz));
      }
    }
  }
}

extern "C" void kernel_launch(void* const* d_in, const int* in_sizes, int n_in,
                              void* d_out, int out_size, void* d_ws, size_t ws_size,
                              hipStream_t stream)
{
  const float* x      = (const float*)d_in[0];
  const float* ln_w   = (const float*)d_in[1];
  const float* ln_b   = (const float*)d_in[2];
  const float* inpw   = (const float*)d_in[3];
  const float* convw  = (const float*)d_in[4];
  const float* convb  = (const float*)d_in[5];
  const float* xpw    = (const float*)d_in[6];
  const float* dtpw   = (const float*)d_in[7];
  const float* dtpb   = (const float*)d_in[8];
  const float* A_log  = (const float*)d_in[9];
  const float* Dmat   = (const float*)d_in[10];
  const float* outw   = (const float*)d_in[11];
  float* out = (float*)d_out;

  // Workspace (~214 MB < 235 MB proven). Liveness aliasing:
  //  wbuf 2MB : per-GEMM bf16 weights (wIn -> wXp -> wOut sequentially)
  //  B ubf 32MB : u_raw (in_proj->conv), then y (pass3->out_proj)
  //  D ucbR 32MB: uc row-major (conv->x_proj,dt_pack); then bc(8.4)+hbuf(16.8)+dts
  //  E xdb 10.5MB f32 (x_proj -> dt_pack, bc_pack)
  //  F: dtT 64MB + uT 32MB + zT 32MB time-major streams; hln(16MB) overlays dtT
  const size_t nIn   = (size_t)2*DI*DM;
  const size_t nXp   = (size_t)160*DI;
  const size_t nOutW = (size_t)DM*DI;
  size_t off = 0;
  char* base = (char*)d_ws;
  auto alloc = [&](size_t bytes)->char*{ char* p = base + off; off += (bytes + 255) & ~(size_t)255; return p; };
  __hip_bfloat16* wbuf = (__hip_bfloat16*)alloc(nIn*2);                 // 2 MB
  __hip_bfloat16* ubf  = (__hip_bfloat16*)alloc((size_t)NROWS*DI*2);    // 32 MB
  char*           ucbR = alloc((size_t)NROWS*DI*2);                     // 32 MB
  float*          xdb  = (float*)alloc((size_t)NROWS*160*4);            // 10.5 MB
  float*          dtT  = (float*)alloc((size_t)NROWS*DI*4);             // 64 MB
  ushort*         uT   = (ushort*)alloc((size_t)NROWS*DI*2);            // 32 MB
  ushort*         zT   = (ushort*)alloc((size_t)NROWS*DI*2);            // 32 MB
  if (ws_size < off) {
    zero_kernel<<<(out_size+255)/256, 256, 0, stream>>>(out, out_size);
    return;
  }
  __hip_bfloat16* hln  = (__hip_bfloat16*)dtT;       // dead before dtT written
  __hip_bfloat16* ucrow = (__hip_bfloat16*)ucbR;     // conv out (dies at dt_pack)
  float* bcb  = (float*)ucbR;                        // bc: 8.4 MB
  float* hbuf = (float*)(ucbR + 8*1024*1024 + 512*1024);     // 16.8 MB
  float* dts  = (float*)(ucbR + 26*1024*1024);               // 0.26 MB

  for (int l = 0; l < 2; ++l) {
    const float* xin = (l == 0) ? x : out;

    cvt_bf16_kernel<<<(int)((nIn+255)/256), 256, 0, stream>>>(inpw + (size_t)l*nIn, wbuf, (int)nIn);
    ln_kernel<<<NROWS/4, 256, 0, stream>>>(xin, ln_w + l*DM, ln_b + l*DM, hln);

    // in_proj u half -> row-major bf16; z half -> TIME-MAJOR bf16
    gemm_mfma<2><<<dim3(DI/128, NROWS/128), 256, 0, stream>>>(
        (const ushort*)hln, (const ushort*)wbuf, ubf, nullptr, NROWS, DI, DM);
    gemm_mfma<3><<<dim3(DI/128, NROWS/128), 256, 0, stream>>>(
        (const ushort*)hln, (const ushort*)(wbuf + (size_t)DI*DM), zT, nullptr, NROWS, DI, DM);

    conv_silu_kernel<<<(NROWS*DI)/256, 256, 0, stream>>>(
        ubf, convw + l*DI*4, convb + l*DI, ucrow);

    cvt_bf16_kernel<<<(int)((nXp+255)/256), 256, 0, stream>>>(xpw + (size_t)l*nXp, wbuf, (int)nXp);
    gemm_mfma<0><<<dim3(2, NROWS/128), 256, 0, stream>>>(
        (const ushort*)ucrow, (const ushort*)wbuf, xdb, nullptr, NROWS, 160, DI);

    dt_pack_kernel<<<dim3(SL/64, DI/64, NB), 256, 0, stream>>>(
        xdb, dtpw + (size_t)l*DI*DTR, dtpb + l*DI, (const ushort*)ucrow, dtT, uT);
    bc_pack_kernel<<<dim3(SL/64, NB), 256, 0, stream>>>(xdb, bcb);

    const float* Al = A_log + (size_t)l*DI*NDS;
    scan_pass1<<<dim3(DI/16, NC, NB), 256, 0, stream>>>(dtT, uT, bcb, Al, hbuf, dts);
    scan_pass2<<<(NB*DI*NDS)/256, 256, 0, stream>>>(Al, dts, hbuf);
    scan_pass3<<<dim3(DI/16, NC, NB), 256, 0, stream>>>(
        dtT, uT, zT, bcb, Al, Dmat + l*DI, hbuf, ubf);

    cvt_bf16_kernel<<<(int)((nOutW+255)/256), 256, 0, stream>>>(outw + (size_t)l*nOutW, wbuf, (int)nOutW);
    gemm_mfma<1><<<dim3(DM/128, NROWS/128), 256, 0, stream>>>(
        (const ushort*)ubf, (const ushort*)wbuf, out, xin, NROWS, DM, DI);
  }
}

// Round 7
// 3260.999 us; speedup vs baseline: 1.9979x; 1.1475x over previous
//
#include <hip/hip_runtime.h>
#include <hip/hip_bf16.h>
#include <math.h>

// Problem constants (fixed by the reference)
#define NB   8
#define SL   2048
#define DM   512
#define DI   1024
#define NDS  64
#define DTR  32
#define NROWS (NB*SL)   // 16384

#define NC  16         // parallel-scan chunks over L
#define LC  (SL/NC)    // 128 steps per chunk
#define ST  8          // time steps per load block in scan kernels

typedef __attribute__((ext_vector_type(8))) short short8;
typedef __attribute__((ext_vector_type(4))) float f32x4;

__device__ __forceinline__ float sigmoidf_(float x){ return 1.0f/(1.0f + __expf(-x)); }

// ---------------- fallback: zero the output (ws too small diagnostic) -------
__global__ void __launch_bounds__(256) zero_kernel(float* __restrict__ p, int n)
{
  const int i = blockIdx.x*256 + threadIdx.x;
  if (i < n) p[i] = 0.0f;
}

// ---------------- f32 -> bf16 elementwise convert ----------------
__global__ void __launch_bounds__(256) cvt_bf16_kernel(const float* __restrict__ s,
    __hip_bfloat16* __restrict__ d, int n)
{
  const int i = blockIdx.x*256 + threadIdx.x;
  if (i < n) d[i] = __float2bfloat16(s[i]);
}

// ---------------- a2 = -exp(A_log) * log2(e)  (so exp(dt*a) = exp2(dt*a2)) --
__global__ void __launch_bounds__(256) a2_kernel(const float* __restrict__ A_log,
    float* __restrict__ a2, int n)
{
  const int i = blockIdx.x*256 + threadIdx.x;
  if (i < n) a2[i] = -__expf(A_log[i]) * 1.4426950408889634f;
}

// ---------------- LayerNorm: one wave per row, bf16 output ----------------
__global__ void __launch_bounds__(256) ln_kernel(const float* __restrict__ x,
    const float* __restrict__ w, const float* __restrict__ b,
    __hip_bfloat16* __restrict__ out)
{
  const int wave = threadIdx.x >> 6;
  const int lane = threadIdx.x & 63;
  const int row  = (blockIdx.x << 2) + wave;
  const float* xr = x + (size_t)row * DM;
  float4 v0 = *(const float4*)(xr + lane*4);
  float4 v1 = *(const float4*)(xr + 256 + lane*4);
  float s = v0.x+v0.y+v0.z+v0.w + v1.x+v1.y+v1.z+v1.w;
  float q = v0.x*v0.x+v0.y*v0.y+v0.z*v0.z+v0.w*v0.w
          + v1.x*v1.x+v1.y*v1.y+v1.z*v1.z+v1.w*v1.w;
  #pragma unroll
  for (int off=1; off<64; off<<=1){ s += __shfl_xor(s, off); q += __shfl_xor(q, off); }
  const float mean = s * (1.0f/DM);
  const float var  = q * (1.0f/DM) - mean*mean;
  const float rstd = rsqrtf(var + 1e-5f);
  float4 w0 = *(const float4*)(w + lane*4);
  float4 w1 = *(const float4*)(w + 256 + lane*4);
  float4 b0 = *(const float4*)(b + lane*4);
  float4 b1 = *(const float4*)(b + 256 + lane*4);
  __hip_bfloat16* orow = out + (size_t)row * DM;
  orow[lane*4+0] = __float2bfloat16((v0.x-mean)*rstd*w0.x + b0.x);
  orow[lane*4+1] = __float2bfloat16((v0.y-mean)*rstd*w0.y + b0.y);
  orow[lane*4+2] = __float2bfloat16((v0.z-mean)*rstd*w0.z + b0.z);
  orow[lane*4+3] = __float2bfloat16((v0.w-mean)*rstd*w0.w + b0.w);
  orow[256+lane*4+0] = __float2bfloat16((v1.x-mean)*rstd*w1.x + b1.x);
  orow[256+lane*4+1] = __float2bfloat16((v1.y-mean)*rstd*w1.y + b1.y);
  orow[256+lane*4+2] = __float2bfloat16((v1.z-mean)*rstd*w1.z + b1.z);
  orow[256+lane*4+3] = __float2bfloat16((v1.w-mean)*rstd*w1.w + b1.w);
}

// ---------------- bf16 MFMA GEMM: C[M,N] = A[M,K] * W[N,K]^T ----------------
// 128x128 tile, BK=32, 4 waves x (4x4 of 16x16x32 MFMA). LDS rows padded to
// 40 ushorts (2-way bank aliasing only = free). Verified round 4.
// MODE: 0 = f32 out, 1 = f32 out + residual, 2 = bf16 row-major out
template<int MODE>
__global__ void __launch_bounds__(256) gemm_mfma(
    const ushort* __restrict__ A, const ushort* __restrict__ W,
    void* __restrict__ Cout, const float* __restrict__ res,
    int M, int N, int K)
{
  __shared__ __align__(16) ushort As[128*40];
  __shared__ __align__(16) ushort Ws[128*40];
  const int t    = threadIdx.x;
  const int m0   = blockIdx.y * 128;
  const int n0   = blockIdx.x * 128;
  const int lane = t & 63;
  const int wv   = t >> 6;
  const int wm   = wv >> 1, wn = wv & 1;
  const int fr   = lane & 15, fq = lane >> 4;

  const int ar0 = t >> 2,        as0 = (t & 3) << 3;
  const int ar1 = (t+256) >> 2,  as1 = as0;
  const int wr0 = min(n0 + ar0, N-1);
  const int wr1 = min(n0 + ar1, N-1);

  f32x4 acc[4][4];
  #pragma unroll
  for (int i=0;i<4;i++)
    #pragma unroll
    for (int j=0;j<4;j++) acc[i][j] = (f32x4){0.f,0.f,0.f,0.f};

  const ushort* Ab = A + (size_t)m0 * K;

  for (int k0 = 0; k0 < K; k0 += 32) {
    const int4 av0 = *(const int4*)(Ab + (size_t)ar0*K + k0 + as0);
    const int4 av1 = *(const int4*)(Ab + (size_t)ar1*K + k0 + as1);
    const int4 wv0 = *(const int4*)(W  + (size_t)wr0*K + k0 + as0);
    const int4 wv1 = *(const int4*)(W  + (size_t)wr1*K + k0 + as1);
    *(int4*)&As[ar0*40 + as0] = av0;
    *(int4*)&As[ar1*40 + as1] = av1;
    *(int4*)&Ws[ar0*40 + as0] = wv0;
    *(int4*)&Ws[ar1*40 + as1] = wv1;
    __syncthreads();
    short8 af[4], wf[4];
    #pragma unroll
    for (int i=0;i<4;i++)
      af[i] = *(const short8*)&As[(wm*64 + i*16 + fr)*40 + fq*8];
    #pragma unroll
    for (int j=0;j<4;j++)
      wf[j] = *(const short8*)&Ws[(wn*64 + j*16 + fr)*40 + fq*8];
    #pragma unroll
    for (int i=0;i<4;i++)
      #pragma unroll
      for (int j=0;j<4;j++)
        acc[i][j] = __builtin_amdgcn_mfma_f32_16x16x32_bf16(af[i], wf[j], acc[i][j], 0, 0, 0);
    __syncthreads();
  }

  #pragma unroll
  for (int j=0;j<4;j++){
    const int n = n0 + wn*64 + j*16 + fr;
    if (n >= N) continue;
    #pragma unroll
    for (int i=0;i<4;i++){
      #pragma unroll
      for (int r=0;r<4;r++){
        const int m = m0 + wm*64 + i*16 + fq*4 + r;
        float v = acc[i][j][r];
        if (MODE == 1) v += res[(size_t)m*N + n];
        if (MODE == 2)
          ((__hip_bfloat16*)Cout)[(size_t)m*N + n] = __float2bfloat16(v);
        else
          ((float*)Cout)[(size_t)m*N + n] = v;
      }
    }
  }
}

// ---------------- Causal depthwise conv (width 4) + SiLU, bf16 in/out -------
__global__ void __launch_bounds__(256) conv_silu_kernel(
    const __hip_bfloat16* __restrict__ u_raw,
    const float* __restrict__ cw, const float* __restrict__ cb,
    __hip_bfloat16* __restrict__ uc)
{
  const int gid = blockIdx.x*256 + threadIdx.x;     // 0 .. NROWS*DI-1
  const int d   = gid & (DI-1);
  const int row = gid >> 10;
  const int l   = row & (SL-1);
  float acc = cb[d];
  const float* w = cw + d*4;
  #pragma unroll
  for (int k=0;k<4;k++){
    const int ll = l-3+k;
    if (ll >= 0) acc += __bfloat162float(u_raw[(size_t)(row-3+k)*DI + d]) * w[k];
  }
  const float s = acc * sigmoidf_(acc);
  uc[gid] = __float2bfloat16(s);
}

// ---------------- dt = softplus(xdb[:, :32] @ dtp_w^T + b), row-major f32 ---
__global__ void __launch_bounds__(256) dt_kernel(const float* __restrict__ xdbl,
    const float* __restrict__ w, const float* __restrict__ bias, float* __restrict__ dt_out)
{
  const int d     = blockIdx.y*256 + threadIdx.x;
  const int rbase = blockIdx.x*64;
  float wr[32];
  #pragma unroll
  for (int i=0;i<8;i++){
    const float4 v = *(const float4*)(w + (size_t)d*DTR + i*4);
    wr[i*4+0]=v.x; wr[i*4+1]=v.y; wr[i*4+2]=v.z; wr[i*4+3]=v.w;
  }
  const float bb = bias[d];
  __shared__ __align__(16) float xd[64][32];
  #pragma unroll
  for (int ii=0; ii<2; ii++){
    const int i  = threadIdx.x + ii*256;
    const int rl = i >> 3, qo = (i & 7) << 2;
    const float4 v = *(const float4*)(xdbl + (size_t)(rbase+rl)*160 + qo);
    *(float4*)&xd[rl][qo] = v;
  }
  __syncthreads();
  for (int rl=0; rl<64; rl++){
    float acc = bb;
    #pragma unroll
    for (int r=0;r<DTR;r++) acc += xd[rl][r]*wr[r];
    const float sp = (acc > 20.0f) ? acc : logf(1.0f + __expf(acc));
    dt_out[(size_t)(rbase+rl)*DI + d] = sp;
  }
}

// ================= Chunked parallel selective scan, d-per-lane =================
// lane = one d channel (64 d per wave); ALL 64 states live in lane registers
// (h[64], a2[64]). No shfl (state reduce is in-lane into 4 split accums), no
// gathers (dt/u/z row-major coalesced; B/C wave-uniform-address broadcast
// float4 loads straight from xdb rows). Rounds 4-6 showed the 4dx16s mapping
// pays ~500 cyc/wave-step in TA-gather + shfl stalls for 256 elems of work;
// this mapping does 4096 elems per wave-step at ~800 essential VALU cycles.

// grid (DI/64, NC/4, NB), block 256 = 4 waves; wave w -> chunk c = by*4+w
__global__ void __launch_bounds__(256) scan_pass1(
    const float* __restrict__ dtb, const ushort* __restrict__ ub,
    const float* __restrict__ xdb, const float* __restrict__ a2b,
    float* __restrict__ hbuf, float* __restrict__ dtsum)
{
  const int lane = threadIdx.x & 63, wave = threadIdx.x >> 6;
  const int c = blockIdx.y*4 + wave, b = blockIdx.z;
  const int d = blockIdx.x*64 + lane;

  float a2r[64], h[64];
  {
    const float* ap = a2b + (size_t)d*NDS;
    #pragma unroll
    for (int i=0;i<16;i++) *(float4*)&a2r[i*4] = *(const float4*)(ap + i*4);
  }
  #pragma unroll
  for (int i=0;i<64;i++) h[i]=0.f;
  float sdt = 0.f;

  const size_t row0 = (size_t)b*SL + (size_t)c*LC;
  const float*  dp  = dtb + row0*DI + d;
  const ushort* up  = ub  + row0*DI + d;
  const float*  xr0 = xdb + row0*160;

  for (int base = 0; base < LC; base += ST) {
    float dts[ST]; unsigned int us[ST];
    #pragma unroll
    for (int t=0;t<ST;t++){
      dts[t] = dp[(size_t)(base+t)*DI];
      us[t]  = up[(size_t)(base+t)*DI];
    }
    #pragma unroll
    for (int t=0;t<ST;t++){
      const float dtv = dts[t];
      const float uu  = __uint_as_float(us[t] << 16);
      const float dtu = dtv*uu;
      sdt += dtv;
      const float* xr = xr0 + (size_t)(base+t)*160;
      #pragma unroll
      for (int g=0; g<4; g++){
        float Bv[16];
        #pragma unroll
        for (int q=0;q<4;q++) *(float4*)&Bv[q*4] = *(const float4*)(xr + 32 + g*16 + q*4);
        #pragma unroll
        for (int j=0;j<16;j++){
          const int s = g*16 + j;
          const float e = exp2f(dtv*a2r[s]);
          h[s] = fmaf(e, h[s], dtu*Bv[j]);
        }
      }
    }
  }
  float* hp = hbuf + (((size_t)c*NB + b)*DI + d)*NDS;
  #pragma unroll
  for (int i=0;i<16;i++) *(float4*)(hp + i*4) = *(const float4*)&h[i*4];
  dtsum[((size_t)c*NB + b)*DI + d] = sdt;
}

// chunk-state propagation, in-place: hbuf[c] := h_start[c]
__global__ void __launch_bounds__(256) scan_pass2(
    const float* __restrict__ A_log, const float* __restrict__ dtsum,
    float* __restrict__ hbuf)
{
  const int tid = blockIdx.x*256 + threadIdx.x;
  const int s = tid & 63, d = (tid >> 6) & (DI-1), b = tid >> 16;
  const float a = -__expf(A_log[(size_t)d*NDS + s]);
  float h = 0.f;
  #pragma unroll
  for (int c = 0; c < NC; c++){
    const size_t idx = (((size_t)c*NB + b)*DI + d)*NDS + s;
    const float he = hbuf[idx];
    hbuf[idx] = h;
    h = __expf(a * dtsum[((size_t)c*NB + b)*DI + d]) * h + he;
  }
}

// grid (DI/64, NC/4, NB), block 256
__global__ void __launch_bounds__(256) scan_pass3(
    const float* __restrict__ dtb, const ushort* __restrict__ ub,
    const ushort* __restrict__ zb, const float* __restrict__ xdb,
    const float* __restrict__ a2b, const float* __restrict__ Dv,
    const float* __restrict__ hbuf, ushort* __restrict__ yg)
{
  const int lane = threadIdx.x & 63, wave = threadIdx.x >> 6;
  const int c = blockIdx.y*4 + wave, b = blockIdx.z;
  const int d = blockIdx.x*64 + lane;

  float a2r[64], h[64];
  {
    const float* ap = a2b + (size_t)d*NDS;
    #pragma unroll
    for (int i=0;i<16;i++) *(float4*)&a2r[i*4] = *(const float4*)(ap + i*4);
  }
  {
    const float* hp = hbuf + (((size_t)c*NB + b)*DI + d)*NDS;
    #pragma unroll
    for (int i=0;i<16;i++) *(float4*)&h[i*4] = *(const float4*)(hp + i*4);
  }
  const float Dval = Dv[d];

  const size_t row0 = (size_t)b*SL + (size_t)c*LC;
  const float*  dp  = dtb + row0*DI + d;
  const ushort* up  = ub  + row0*DI + d;
  const ushort* zp  = zb  + row0*DI + d;
  const float*  xr0 = xdb + row0*160;
  ushort*       yp  = yg  + row0*DI + d;

  for (int base = 0; base < LC; base += ST) {
    float dts[ST]; unsigned int us[ST], zs[ST];
    #pragma unroll
    for (int t=0;t<ST;t++){
      dts[t] = dp[(size_t)(base+t)*DI];
      us[t]  = up[(size_t)(base+t)*DI];
      zs[t]  = zp[(size_t)(base+t)*DI];
    }
    #pragma unroll
    for (int t=0;t<ST;t++){
      const float dtv = dts[t];
      const float uu  = __uint_as_float(us[t] << 16);
      const float zz  = __uint_as_float(zs[t] << 16);
      const float dtu = dtv*uu;
      const float* xr = xr0 + (size_t)(base+t)*160;
      float acc0=0.f, acc1=0.f, acc2=0.f, acc3=0.f;
      #pragma unroll
      for (int g=0; g<4; g++){
        float Bv[16], Cv[16];
        #pragma unroll
        for (int q=0;q<4;q++){
          *(float4*)&Bv[q*4] = *(const float4*)(xr + 32 + g*16 + q*4);
          *(float4*)&Cv[q*4] = *(const float4*)(xr + 96 + g*16 + q*4);
        }
        #pragma unroll
        for (int j=0;j<16;j++){
          const int s = g*16 + j;
          const float e = exp2f(dtv*a2r[s]);
          h[s] = fmaf(e, h[s], dtu*Bv[j]);
          if ((j&3)==0)      acc0 = fmaf(h[s], Cv[j], acc0);
          else if ((j&3)==1) acc1 = fmaf(h[s], Cv[j], acc1);
          else if ((j&3)==2) acc2 = fmaf(h[s], Cv[j], acc2);
          else               acc3 = fmaf(h[s], Cv[j], acc3);
        }
      }
      const float p = (acc0+acc1) + (acc2+acc3);
      const float y = p + uu*Dval;
      const float g = y * zz * sigmoidf_(zz);
      yp[(size_t)(base+t)*DI] = __bfloat16_as_ushort(__float2bfloat16(g));
    }
  }
}

extern "C" void kernel_launch(void* const* d_in, const int* in_sizes, int n_in,
                              void* d_out, int out_size, void* d_ws, size_t ws_size,
                              hipStream_t stream)
{
  const float* x      = (const float*)d_in[0];
  const float* ln_w   = (const float*)d_in[1];
  const float* ln_b   = (const float*)d_in[2];
  const float* inpw   = (const float*)d_in[3];
  const float* convw  = (const float*)d_in[4];
  const float* convb  = (const float*)d_in[5];
  const float* xpw    = (const float*)d_in[6];
  const float* dtpw   = (const float*)d_in[7];
  const float* dtpb   = (const float*)d_in[8];
  const float* A_log  = (const float*)d_in[9];
  const float* Dmat   = (const float*)d_in[10];
  const float* outw   = (const float*)d_in[11];
  float* out = (float*)d_out;

  // Workspace (~207 MB < 235 MB proven). Aliasing: hln overlays dtb (hln dead
  // before dt_kernel writes dtb); y overlays ubf (u_raw dead after conv).
  const size_t nIn   = (size_t)2*DI*DM;
  const size_t nXp   = (size_t)160*DI;
  const size_t nOutW = (size_t)DM*DI;
  size_t off = 0;
  char* base = (char*)d_ws;
  auto alloc = [&](size_t bytes)->char*{ char* p = base + off; off += (bytes + 255) & ~(size_t)255; return p; };
  __hip_bfloat16* wbuf = (__hip_bfloat16*)alloc(nIn*2);                 // 2 MB
  __hip_bfloat16* ubf  = (__hip_bfloat16*)alloc((size_t)NROWS*DI*2);    // 32 MB (u_raw -> y)
  __hip_bfloat16* zbf  = (__hip_bfloat16*)alloc((size_t)NROWS*DI*2);    // 32 MB
  __hip_bfloat16* ucb  = (__hip_bfloat16*)alloc((size_t)NROWS*DI*2);    // 32 MB
  float*          xdb  = (float*)alloc((size_t)NROWS*160*4);            // 10.5 MB
  float*          dtb  = (float*)alloc((size_t)NROWS*DI*4);             // 64 MB
  float*          hbuf = (float*)alloc((size_t)NC*NB*DI*NDS*4);         // 33.6 MB
  float*          dts  = (float*)alloc((size_t)NC*NB*DI*4);             // 0.5 MB
  float*          a2b  = (float*)alloc((size_t)DI*NDS*4);               // 0.26 MB
  if (ws_size < off) {
    zero_kernel<<<(out_size+255)/256, 256, 0, stream>>>(out, out_size);
    return;
  }
  __hip_bfloat16* hln = (__hip_bfloat16*)dtb;   // overlay

  for (int l = 0; l < 2; ++l) {
    const float* xin = (l == 0) ? x : out;
    const float* Al  = A_log + (size_t)l*DI*NDS;

    cvt_bf16_kernel<<<(int)((nIn+255)/256), 256, 0, stream>>>(inpw + (size_t)l*nIn, wbuf, (int)nIn);
    ln_kernel<<<NROWS/4, 256, 0, stream>>>(xin, ln_w + l*DM, ln_b + l*DM, hln);

    gemm_mfma<2><<<dim3(DI/128, NROWS/128), 256, 0, stream>>>(
        (const ushort*)hln, (const ushort*)wbuf, ubf, nullptr, NROWS, DI, DM);
    gemm_mfma<2><<<dim3(DI/128, NROWS/128), 256, 0, stream>>>(
        (const ushort*)hln, (const ushort*)(wbuf + (size_t)DI*DM), zbf, nullptr, NROWS, DI, DM);

    conv_silu_kernel<<<(NROWS*DI)/256, 256, 0, stream>>>(
        ubf, convw + l*DI*4, convb + l*DI, ucb);

    cvt_bf16_kernel<<<(int)((nXp+255)/256), 256, 0, stream>>>(xpw + (size_t)l*nXp, wbuf, (int)nXp);
    gemm_mfma<0><<<dim3(2, NROWS/128), 256, 0, stream>>>(
        (const ushort*)ucb, (const ushort*)wbuf, xdb, nullptr, NROWS, 160, DI);

    dt_kernel<<<dim3(NROWS/64, DI/256), 256, 0, stream>>>(
        xdb, dtpw + (size_t)l*DI*DTR, dtpb + l*DI, dtb);
    a2_kernel<<<(DI*NDS)/256, 256, 0, stream>>>(Al, a2b, DI*NDS);

    scan_pass1<<<dim3(DI/64, NC/4, NB), 256, 0, stream>>>(
        dtb, (const ushort*)ucb, xdb, a2b, hbuf, dts);
    scan_pass2<<<(NB*DI*NDS)/256, 256, 0, stream>>>(Al, dts, hbuf);
    scan_pass3<<<dim3(DI/64, NC/4, NB), 256, 0, stream>>>(
        dtb, (const ushort*)ucb, (const ushort*)zbf, xdb, a2b, Dmat + l*DI,
        hbuf, (ushort*)ubf);

    cvt_bf16_kernel<<<(int)((nOutW+255)/256), 256, 0, stream>>>(outw + (size_t)l*nOutW, wbuf, (int)nOutW);
    gemm_mfma<1><<<dim3(DM/128, NROWS/128), 256, 0, stream>>>(
        (const ushort*)ubf, (const ushort*)wbuf, out, xin, NROWS, DM, DI);
  }
}